// Round 1
// baseline (87.836 us; speedup 1.0000x reference)
//
#include <hip/hip_runtime.h>
#include <hip/hip_bf16.h>
#include <math.h>

// Problem: x (64, 2, 512, 512) f32. x0 = x[:,0] -> (64,512,512).
// n[v] = sqrt(sum_{b,f} x0[b,v,f]^2)
// out[b,i,j] = (sum_f x0[b,i,f]*x0[b,j,f]) / (n[i]*n[j])

#define BATCH 64
#define VDIM 512
#define FDIM 512
#define X_BATCH_STRIDE (2 * VDIM * FDIM)   // 524288 floats per batch (T=2)
#define OUT_BATCH_STRIDE (VDIM * VDIM)     // 262144 floats

typedef __bf16 bf16x8 __attribute__((ext_vector_type(8)));
typedef float f32x4 __attribute__((ext_vector_type(4)));

#define BM 128
#define BK 32
#define LDS_STRIDE 40   // bf16 elems per row: 80 bytes -> 16B-aligned, 2-way-free bank pattern

// ---------------- norm kernel: one block per v ----------------
__global__ __launch_bounds__(256) void norm_kernel(const float* __restrict__ x,
                                                   float* __restrict__ inv_n) {
    const int v = blockIdx.x;
    const int tid = threadIdx.x;
    float s = 0.f;
    // 64 batches x 128 float4 per (b, v) row = 8192 float4 chunks
    const float4* xf4 = (const float4*)x;
    for (int c = tid; c < 8192; c += 256) {
        int b = c >> 7;
        int f4 = c & 127;
        float4 d = xf4[(size_t)b * (X_BATCH_STRIDE / 4) + (size_t)v * (FDIM / 4) + f4];
        s += d.x * d.x + d.y * d.y + d.z * d.z + d.w * d.w;
    }
    // wave reduce (wave = 64)
    #pragma unroll
    for (int off = 32; off > 0; off >>= 1) s += __shfl_down(s, off, 64);
    __shared__ float partial[4];
    if ((tid & 63) == 0) partial[tid >> 6] = s;
    __syncthreads();
    if (tid == 0) {
        float t = partial[0] + partial[1] + partial[2] + partial[3];
        inv_n[v] = 1.0f / sqrtf(t);
    }
}

// ---------------- gram kernel: 64 batches x (4x4) tiles of 128x128 ----------------
__global__ __launch_bounds__(256) void gram_kernel(const float* __restrict__ x,
                                                   const float* __restrict__ inv_n,
                                                   float* __restrict__ out) {
    __shared__ __bf16 As[BM * LDS_STRIDE];
    __shared__ __bf16 Bs[BM * LDS_STRIDE];

    const int bid = blockIdx.x;
    const int batch = bid >> 4;
    const int tile = bid & 15;
    const int ti = tile >> 2;
    const int tj = tile & 3;

    const float* xb = x + (size_t)batch * X_BATCH_STRIDE;
    const float* Abase = xb + (size_t)(ti * BM) * FDIM;
    const float* Bbase = xb + (size_t)(tj * BM) * FDIM;

    const int tid = threadIdx.x;
    const int lane = tid & 63;
    const int wave = tid >> 6;       // 0..3
    const int wr = wave >> 1;        // 0..1
    const int wc = wave & 1;         // 0..1

    const int srow = tid >> 1;       // 0..127 (staging row)
    const int sseg = tid & 1;        // 0..1   (16-float segment)

    f32x4 acc[4][4];
    #pragma unroll
    for (int m = 0; m < 4; ++m)
        #pragma unroll
        for (int n = 0; n < 4; ++n)
            acc[m][n] = (f32x4){0.f, 0.f, 0.f, 0.f};

    for (int kk = 0; kk < FDIM; kk += BK) {
        // ---- stage A & B tiles: global f32 -> regs -> bf16 -> LDS ----
        const float4* ga = (const float4*)(Abase + (size_t)srow * FDIM + kk + sseg * 16);
        const float4* gb = (const float4*)(Bbase + (size_t)srow * FDIM + kk + sseg * 16);
        float4 a0 = ga[0], a1 = ga[1], a2 = ga[2], a3 = ga[3];
        float4 b0 = gb[0], b1 = gb[1], b2 = gb[2], b3 = gb[3];

        float va[16] = {a0.x, a0.y, a0.z, a0.w, a1.x, a1.y, a1.z, a1.w,
                        a2.x, a2.y, a2.z, a2.w, a3.x, a3.y, a3.z, a3.w};
        float vb[16] = {b0.x, b0.y, b0.z, b0.w, b1.x, b1.y, b1.z, b1.w,
                        b2.x, b2.y, b2.z, b2.w, b3.x, b3.y, b3.z, b3.w};
        bf16x8 pa0, pa1, pb0, pb1;
        #pragma unroll
        for (int j = 0; j < 8; ++j) {
            pa0[j] = (__bf16)va[j];
            pa1[j] = (__bf16)va[8 + j];
            pb0[j] = (__bf16)vb[j];
            pb1[j] = (__bf16)vb[8 + j];
        }
        bf16x8* wa = (bf16x8*)&As[srow * LDS_STRIDE + sseg * 16];
        bf16x8* wb = (bf16x8*)&Bs[srow * LDS_STRIDE + sseg * 16];
        wa[0] = pa0; wa[1] = pa1;
        wb[0] = pb0; wb[1] = pb1;

        __syncthreads();

        // ---- fragments ----
        bf16x8 af[4], bfr[4];
        #pragma unroll
        for (int m = 0; m < 4; ++m) {
            int row = wr * 64 + m * 16 + (lane & 15);
            af[m] = *(const bf16x8*)&As[row * LDS_STRIDE + (lane >> 4) * 8];
        }
        #pragma unroll
        for (int n = 0; n < 4; ++n) {
            int row = wc * 64 + n * 16 + (lane & 15);
            bfr[n] = *(const bf16x8*)&Bs[row * LDS_STRIDE + (lane >> 4) * 8];
        }

        #pragma unroll
        for (int m = 0; m < 4; ++m)
            #pragma unroll
            for (int n = 0; n < 4; ++n)
                acc[m][n] = __builtin_amdgcn_mfma_f32_16x16x32_bf16(af[m], bfr[n], acc[m][n], 0, 0, 0);

        __syncthreads();
    }

    // ---- epilogue: scale by inv_n[i]*inv_n[j], store ----
    const int rowbase = ti * BM + wr * 64;
    const int colbase = tj * BM + wc * 64;
    float* ob = out + (size_t)batch * OUT_BATCH_STRIDE;

    float si[16];
    #pragma unroll
    for (int m = 0; m < 4; ++m)
        #pragma unroll
        for (int q = 0; q < 4; ++q)
            si[m * 4 + q] = inv_n[rowbase + m * 16 + (lane >> 4) * 4 + q];

    #pragma unroll
    for (int n = 0; n < 4; ++n) {
        int j = colbase + n * 16 + (lane & 15);
        float sj = inv_n[j];
        #pragma unroll
        for (int m = 0; m < 4; ++m) {
            #pragma unroll
            for (int q = 0; q < 4; ++q) {
                int i = rowbase + m * 16 + (lane >> 4) * 4 + q;
                ob[(size_t)i * VDIM + j] = acc[m][n][q] * si[m * 4 + q] * sj;
            }
        }
    }
}

extern "C" void kernel_launch(void* const* d_in, const int* in_sizes, int n_in,
                              void* d_out, int out_size, void* d_ws, size_t ws_size,
                              hipStream_t stream) {
    const float* x = (const float*)d_in[0];
    float* out = (float*)d_out;
    float* inv_n = (float*)d_ws;   // 512 floats

    norm_kernel<<<VDIM, 256, 0, stream>>>(x, inv_n);
    gram_kernel<<<BATCH * 16, 256, 0, stream>>>(x, inv_n, out);
}

// Round 2
// 50.062 us; speedup vs baseline: 1.7545x; 1.7545x over previous
//
#include <hip/hip_runtime.h>
#include <hip/hip_bf16.h>
#include <math.h>

// Problem: x (64, 2, 512, 512) f32. x0 = x[:,0] -> (64,512,512).
// n[v] = sqrt(sum_{b,f} x0[b,v,f]^2)
// out[b,i,j] = (sum_f x0[b,i,f]*x0[b,j,f]) / (n[i]*n[j])

#define BATCH 64
#define VDIM 512
#define FDIM 512
#define XBS (2 * VDIM * FDIM)      // x batch stride in floats (T=2)
#define OBS (VDIM * VDIM)          // out batch stride in floats

typedef __bf16 bf16x8 __attribute__((ext_vector_type(8)));
typedef __bf16 bf16x4 __attribute__((ext_vector_type(4)));
typedef float f32x4 __attribute__((ext_vector_type(4)));

#define BM 128
#define BK 64                      // bf16 elems per K-step

// ws layout: [0, 33554432): bf16 x0 copy (64*512*512); then f32 inv_n[512]
#define INVN_OFF 33554432

// global -> LDS direct copy, 16B per lane (dest is wave-uniform base + lane*16)
#define GLL16(g, l)                                                          \
    __builtin_amdgcn_global_load_lds(                                        \
        (const __attribute__((address_space(1))) void*)(g),                  \
        (__attribute__((address_space(3))) void*)(l), 16, 0, 0)

// ---------------- fused norm + bf16-convert kernel: one block per v ----------------
__global__ __launch_bounds__(256) void cvt_norm_kernel(const float* __restrict__ x,
                                                       __bf16* __restrict__ xb,
                                                       float* __restrict__ inv_n) {
    const int v = blockIdx.x;
    const int tid = threadIdx.x;
    float s = 0.f;
    const float4* xf4 = (const float4*)x;
    // 64 batches x 128 float4 per (b, v) row
    for (int c = tid; c < 8192; c += 256) {
        int b = c >> 7;
        int f4 = c & 127;
        float4 d = xf4[(size_t)b * (XBS / 4) + (size_t)v * (FDIM / 4) + f4];
        s += d.x * d.x + d.y * d.y + d.z * d.z + d.w * d.w;
        bf16x4 p;
        p[0] = (__bf16)d.x; p[1] = (__bf16)d.y; p[2] = (__bf16)d.z; p[3] = (__bf16)d.w;
        *(bf16x4*)&xb[(size_t)b * (VDIM * FDIM) + (size_t)v * FDIM + f4 * 4] = p;
    }
    #pragma unroll
    for (int off = 32; off > 0; off >>= 1) s += __shfl_down(s, off, 64);
    __shared__ float partial[4];
    if ((tid & 63) == 0) partial[tid >> 6] = s;
    __syncthreads();
    if (tid == 0) {
        float t = partial[0] + partial[1] + partial[2] + partial[3];
        inv_n[v] = 1.0f / sqrtf(t);
    }
}

// ---------------- gram kernel: bf16 global_load_lds + swizzled LDS ----------------
__global__ __launch_bounds__(256) void gram_kernel(const __bf16* __restrict__ xb,
                                                   const float* __restrict__ inv_n,
                                                   float* __restrict__ out) {
    __shared__ __bf16 As[BM * BK];   // 16 KB, linear [128][64] (+XOR swizzle via src)
    __shared__ __bf16 Bs[BM * BK];

    // XCD chunked swizzle: 1024 blocks / 8 XCDs = 128 contiguous logical wgs each
    const int bid = blockIdx.x;
    const int wg = (bid & 7) * 128 + (bid >> 3);
    const int batch = wg >> 4;
    const int tile = wg & 15;
    const int ti = tile >> 2;
    const int tj = tile & 3;

    const __bf16* xbb = xb + (size_t)batch * (VDIM * FDIM);
    const int tid = threadIdx.x;
    const int lane = tid & 63;
    const int wave = tid >> 6;     // 0..3
    const int wr = wave >> 1;      // 0..1
    const int wc = wave & 1;       // 0..1

    // ---- staging addresses (constant per thread; only kk advances) ----
    // chunk c = it*256 + tid in [0,1024): row = c>>3, cc = c&7
    // LDS chunk (row,cc) holds global 16B-chunk (row, cc ^ (row&7))  [both-sides XOR]
    const __bf16* gA[4];
    const __bf16* gB[4];
    __bf16* la[4];
    __bf16* lb[4];
    #pragma unroll
    for (int it = 0; it < 4; ++it) {
        int c = it * 256 + tid;
        int row = c >> 3;
        int cs = (c & 7) ^ (row & 7);
        gA[it] = xbb + (size_t)(ti * BM + row) * FDIM + cs * 8;
        gB[it] = xbb + (size_t)(tj * BM + row) * FDIM + cs * 8;
        la[it] = &As[c * 8];
        lb[it] = &Bs[c * 8];
    }

    // ---- fragment LDS byte offsets (constant per lane) ----
    // element (r, k=ks*32+(lane>>4)*8) lives at LDS chunk (r, (ks*4+(lane>>4)) ^ (r&7))
    int offA[2][4], offB[2][4];
    #pragma unroll
    for (int ks = 0; ks < 2; ++ks) {
        #pragma unroll
        for (int m = 0; m < 4; ++m) {
            int rA = wr * 64 + m * 16 + (lane & 15);
            int rB = wc * 64 + m * 16 + (lane & 15);
            int gch = ks * 4 + (lane >> 4);
            offA[ks][m] = rA * (BK * 2) + ((gch ^ (rA & 7)) * 16);
            offB[ks][m] = rB * (BK * 2) + ((gch ^ (rB & 7)) * 16);
        }
    }

    f32x4 acc[4][4];
    #pragma unroll
    for (int m = 0; m < 4; ++m)
        #pragma unroll
        for (int n = 0; n < 4; ++n)
            acc[m][n] = (f32x4){0.f, 0.f, 0.f, 0.f};

    for (int kk = 0; kk < FDIM; kk += BK) {
        #pragma unroll
        for (int it = 0; it < 4; ++it) {
            GLL16(gA[it] + kk, la[it]);
            GLL16(gB[it] + kk, lb[it]);
        }
        __syncthreads();   // compiler emits vmcnt(0) drain before barrier

        #pragma unroll
        for (int ks = 0; ks < 2; ++ks) {
            bf16x8 af[4], bfr[4];
            #pragma unroll
            for (int m = 0; m < 4; ++m) {
                af[m]  = *(const bf16x8*)((const char*)As + offA[ks][m]);
                bfr[m] = *(const bf16x8*)((const char*)Bs + offB[ks][m]);
            }
            #pragma unroll
            for (int m = 0; m < 4; ++m)
                #pragma unroll
                for (int n = 0; n < 4; ++n)
                    acc[m][n] = __builtin_amdgcn_mfma_f32_16x16x32_bf16(af[m], bfr[n], acc[m][n], 0, 0, 0);
        }
        __syncthreads();
    }

    // ---- epilogue: scale by inv_n[i]*inv_n[j], store ----
    const int rowbase = ti * BM + wr * 64;
    const int colbase = tj * BM + wc * 64;
    float* ob = out + (size_t)batch * OBS;

    float si[16];
    #pragma unroll
    for (int m = 0; m < 4; ++m)
        #pragma unroll
        for (int q = 0; q < 4; ++q)
            si[m * 4 + q] = inv_n[rowbase + m * 16 + (lane >> 4) * 4 + q];

    #pragma unroll
    for (int n = 0; n < 4; ++n) {
        int j = colbase + n * 16 + (lane & 15);
        float sj = inv_n[j];
        #pragma unroll
        for (int m = 0; m < 4; ++m) {
            #pragma unroll
            for (int q = 0; q < 4; ++q) {
                int i = rowbase + m * 16 + (lane >> 4) * 4 + q;
                ob[(size_t)i * VDIM + j] = acc[m][n][q] * si[m * 4 + q] * sj;
            }
        }
    }
}

extern "C" void kernel_launch(void* const* d_in, const int* in_sizes, int n_in,
                              void* d_out, int out_size, void* d_ws, size_t ws_size,
                              hipStream_t stream) {
    const float* x = (const float*)d_in[0];
    float* out = (float*)d_out;
    __bf16* xbf = (__bf16*)d_ws;
    float* inv_n = (float*)((char*)d_ws + INVN_OFF);

    cvt_norm_kernel<<<VDIM, 256, 0, stream>>>(x, xbf, inv_n);
    gram_kernel<<<BATCH * 16, 256, 0, stream>>>(xbf, inv_n, out);
}